// Round 1
// baseline (127101.404 us; speedup 1.0000x reference)
//
#include <hip/hip_runtime.h>
#include <math.h>

#define BB   256
#define TN   1024
#define HH   512
#define MB   4
#define NTHR 1024
#define NBLK (BB/MB)

#define OFF_KEYS 0L
#define OFF_PRS  524288L
#define OFF_HS   1572864L
#define OFF_TM   135790592L

__device__ __forceinline__ float sigm(float x) { return 1.0f / (1.0f + expf(-x)); }

__global__ __launch_bounds__(NTHR) void rnn_fused(
    const float* __restrict__ in,
    const float* __restrict__ w_in, const float* __restrict__ b_in,
    const float* __restrict__ w_rec, const float* __restrict__ b_rec,
    const float* __restrict__ w_key, const float* __restrict__ b_key,
    const float* __restrict__ z,
    float* __restrict__ out)
{
    __shared__ __align__(16) float tbuf[MB][HH][16];   // 128 KB: 16-step hs tile
    __shared__ __align__(16) float hbuf[2][MB][HH];    // 16 KB: h double buffer
    __shared__ float bsum[HH];                         // b_in + b_rec
    __shared__ float wk[2][HH];                        // w_key rows
    __shared__ float inp6[MB][8];
    __shared__ float kred[16][MB][2];
    __shared__ int   idx_sh[MB];

    const int tid = threadIdx.x;
    const int b0  = blockIdx.x * MB;
    const int gr  = tid >> 4;     // 64 groups of 16 lanes
    const int g   = tid & 15;
    const int wv  = tid >> 6;     // wave id (16 waves)
    const int ln  = tid & 63;

    // ---------------- init ----------------
    for (int i = tid; i < MB * HH; i += NTHR) {
        int b = i >> 9, j = i & (HH - 1);
        hbuf[0][b][j] = 0.0f;   // h at t=0
        tbuf[b][j][0] = 0.0f;   // hs column t=0 (zeros)
    }
    for (int j = tid; j < HH; j += NTHR) {
        bsum[j]  = b_in[j] + b_rec[j];
        wk[0][j] = w_key[j];
        wk[1][j] = w_key[HH + j];
    }
    // argmax(tm1[b,:]) first-occurrence, one wave per batch
    if (wv < MB) {
        const float* tm1p = in + (long)(b0 + wv) * 8 * TN + 6 * TN;
        float bv = -3.0e38f; int bi = 0;
        for (int i = 0; i < TN / 64; ++i) {
            int t = i * 64 + ln;
            float v = tm1p[t];
            if (v > bv) { bv = v; bi = t; }
        }
        for (int m = 1; m < 64; m <<= 1) {
            float ov = __shfl_xor(bv, m);
            int   oi = __shfl_xor(bi, m);
            if (ov > bv || (ov == bv && oi < bi)) { bv = ov; bi = oi; }
        }
        if (ln == 0) idx_sh[wv] = bi;
    }
    // tm_modified[:,0,:] = tm1 (full row copy, float4-coalesced)
    {
        int b = tid >> 8, tq = tid & 255;
        const float4 v = *(const float4*)(in + (long)(b0 + b) * 8 * TN + 6 * TN + tq * 4);
        *(float4*)(out + OFF_TM + (long)(b0 + b) * 2 * TN + tq * 4) = v;
    }
    if (tid < MB) {
        int b = b0 + tid;
        out[OFF_TM + (long)b * 2 * TN + TN] = in[(long)b * 8 * TN + 7 * TN]; // tm2[:,0]
        out[OFF_KEYS + (long)b * 2 * TN]       = 0.0f;
        out[OFF_KEYS + (long)b * 2 * TN + TN]  = 0.0f;
        float* pb = out + OFF_PRS + (long)b * 4 * TN;
        pb[0] = 0.0f; pb[TN] = 0.0f; pb[2 * TN] = 0.0f; pb[3 * TN] = 0.0f;
    }

    float kh = 1.0f, off = 0.0f;   // carry (threads 0..3 own batch b=tid)
    int side_pre = 1;
    __syncthreads();
    const int idxm = (tid < MB) ? idx_sh[tid] : 0;

    // ---------------- time loop ----------------
    for (int t = 1; t < TN; ++t) {
        // ---- stage phase: per-batch scalar logic (threads 0..3) ----
        if (tid < MB) {
            const int b = tid;
            if (t > 1) {  // finalize key of step t-1 from kred partials
                float k0s = 0.0f, k1s = 0.0f;
                #pragma unroll
                for (int w = 0; w < 16; ++w) { k0s += kred[w][b][0]; k1s += kred[w][b][1]; }
                float key0 = sigm(k0s + b_key[0]);
                float key1 = sigm(k1s + b_key[1]);
                out[OFF_KEYS + (long)(b0 + b) * 2 * TN + (t - 1)]      = key0;
                out[OFF_KEYS + (long)(b0 + b) * 2 * TN + TN + (t - 1)] = key1;
                kh = key0;
            }
            const float* inb = in + (long)(b0 + b) * 8 * TN;
            const float ap0 = inb[0 * TN + t], ap1 = inb[1 * TN + t];
            const float a0  = inb[2 * TN + t], a1  = inb[3 * TN + t];
            const float a2  = inb[4 * TN + t], a3  = inb[5 * TN + t];
            const float t1  = inb[6 * TN + t], t2o = inb[7 * TN + t];
            const float zt  = z[(long)(t - 1) * BB + b0 + b];
            const int side  = (kh > 0.5f);
            const float asum0 = a0 * kh + a2 * (1.0f - kh);
            const float asum1 = a1 * kh + a3 * (1.0f - kh);
            const int closer1 = (fabsf(ap0 - t1) <= fabsf(ap1 - t1));
            const int done    = (t > idxm);
            const int switched = ((side != side_pre) && done && (side != closer1));
            const float t2c = t2o + off;
            if (switched) off += zt * fabsf(0.05f * t2c);
            const float t2e = t2o + off;
            side_pre = side;
            float q0 = (t1 - ap0) / (0.15f * ap0);  float pr10 = (t1 == 0.0f) ? 0.0f : q0 * q0;
            float q1 = (t1 - ap1) / (0.15f * ap1);  float pr11 = (t1 == 0.0f) ? 0.0f : q1 * q1;
            float q2 = (t2e - asum0) / (0.15f * asum0); float pr20 = (t2e == 0.0f) ? 0.0f : q2 * q2;
            float q3 = (t2e - asum1) / (0.15f * asum1); float pr21 = (t2e == 0.0f) ? 0.0f : q3 * q3;
            float* pb = out + OFF_PRS + (long)(b0 + b) * 4 * TN + t;
            pb[0] = pr10; pb[TN] = pr11; pb[2 * TN] = pr20; pb[3 * TN] = pr21;
            out[OFF_TM + (long)(b0 + b) * 2 * TN + TN + t] = t2e;
            inp6[b][0] = ap0; inp6[b][1] = ap1; inp6[b][2] = asum0;
            inp6[b][3] = asum1; inp6[b][4] = t1; inp6[b][5] = t2e;
        }
        __syncthreads();   // barrier A

        // ---- recurrent GEMV: 64 groups x 16 lanes; each group owns 8 rows, 4 batches ----
        const int rd = (t - 1) & 1, wr = t & 1;
        float acc[8][4];
        #pragma unroll
        for (int r = 0; r < 8; ++r) { acc[r][0] = 0.f; acc[r][1] = 0.f; acc[r][2] = 0.f; acc[r][3] = 0.f; }
        const float* hb = &hbuf[rd][0][0];
        for (int kk = 0; kk < 8; ++kk) {
            const int k0 = kk * 64 + g * 4;
            const float4 h40 = *(const float4*)(hb + 0 * HH + k0);
            const float4 h41 = *(const float4*)(hb + 1 * HH + k0);
            const float4 h42 = *(const float4*)(hb + 2 * HH + k0);
            const float4 h43 = *(const float4*)(hb + 3 * HH + k0);
            #pragma unroll
            for (int r = 0; r < 8; ++r) {
                const float4 w4 = *(const float4*)(w_rec + (long)(r * 64 + gr) * HH + k0);
                acc[r][0] = fmaf(w4.x, h40.x, fmaf(w4.y, h40.y, fmaf(w4.z, h40.z, fmaf(w4.w, h40.w, acc[r][0]))));
                acc[r][1] = fmaf(w4.x, h41.x, fmaf(w4.y, h41.y, fmaf(w4.z, h41.z, fmaf(w4.w, h41.w, acc[r][1]))));
                acc[r][2] = fmaf(w4.x, h42.x, fmaf(w4.y, h42.y, fmaf(w4.z, h42.z, fmaf(w4.w, h42.w, acc[r][2]))));
                acc[r][3] = fmaf(w4.x, h43.x, fmaf(w4.y, h43.y, fmaf(w4.z, h43.z, fmaf(w4.w, h43.w, acc[r][3]))));
            }
        }
        // 16-lane butterfly reduce (width 16) — every lane ends with full sums
        #pragma unroll
        for (int r = 0; r < 8; ++r) {
            #pragma unroll
            for (int b = 0; b < MB; ++b) {
                float v = acc[r][b];
                v += __shfl_xor(v, 1, 16);
                v += __shfl_xor(v, 2, 16);
                v += __shfl_xor(v, 4, 16);
                v += __shfl_xor(v, 8, 16);
                acc[r][b] = v;
            }
        }
        // finalize: lanes g<4 own batch b=g for this group's 8 rows
        float kacc0 = 0.0f, kacc1 = 0.0f;
        if (g < MB) {
            const int b = g;
            #pragma unroll
            for (int r = 0; r < 8; ++r) {
                const int j = r * 64 + gr;
                const float* wi = w_in + j * 6;
                float s = acc[r][b] + bsum[j]
                        + wi[0] * inp6[b][0] + wi[1] * inp6[b][1] + wi[2] * inp6[b][2]
                        + wi[3] * inp6[b][3] + wi[4] * inp6[b][4] + wi[5] * inp6[b][5];
                const float h = tanhf(s);
                hbuf[wr][b][j]    = h;
                tbuf[b][j][t & 15] = h;
                kacc0 = fmaf(h, wk[0][j], kacc0);
                kacc1 = fmaf(h, wk[1][j], kacc1);
            }
        }
        // cross-group (intra-wave) reduce of key partials, then publish per-wave
        kacc0 += __shfl_xor(kacc0, 16); kacc0 += __shfl_xor(kacc0, 32);
        kacc1 += __shfl_xor(kacc1, 16); kacc1 += __shfl_xor(kacc1, 32);
        if (ln < MB) { kred[wv][ln][0] = kacc0; kred[wv][ln][1] = kacc1; }
        __syncthreads();   // barrier B

        // ---- hs flush: every 16 steps write full 64B lines ----
        if ((t & 15) == 15) {
            const int t0 = t & ~15;
            #pragma unroll
            for (int i = 0; i < 8; ++i) {
                const int f = i * NTHR + tid;       // 0..8191 float4s
                const int b = f >> 11, rem = f & 2047;
                const int j = rem >> 2, q = rem & 3;
                const float4 v = *(const float4*)&tbuf[b][j][q * 4];
                *(float4*)(out + OFF_HS + ((long)(b0 + b) * HH + j) * TN + t0 + q * 4) = v;
            }
        }
    }
    // epilogue: keys for t = 1023
    if (tid < MB) {
        const int b = tid;
        float k0s = 0.0f, k1s = 0.0f;
        #pragma unroll
        for (int w = 0; w < 16; ++w) { k0s += kred[w][b][0]; k1s += kred[w][b][1]; }
        out[OFF_KEYS + (long)(b0 + b) * 2 * TN + (TN - 1)]      = sigm(k0s + b_key[0]);
        out[OFF_KEYS + (long)(b0 + b) * 2 * TN + TN + (TN - 1)] = sigm(k1s + b_key[1]);
    }
}

extern "C" void kernel_launch(void* const* d_in, const int* in_sizes, int n_in,
                              void* d_out, int out_size, void* d_ws, size_t ws_size,
                              hipStream_t stream) {
    (void)in_sizes; (void)n_in; (void)out_size; (void)d_ws; (void)ws_size;
    const float* in    = (const float*)d_in[0];
    const float* w_in  = (const float*)d_in[1];
    const float* b_in  = (const float*)d_in[2];
    const float* w_rec = (const float*)d_in[3];
    const float* b_rec = (const float*)d_in[4];
    const float* w_key = (const float*)d_in[5];
    const float* b_key = (const float*)d_in[6];
    const float* z     = (const float*)d_in[7];
    float* out = (float*)d_out;
    hipLaunchKernelGGL(rnn_fused, dim3(NBLK), dim3(NTHR), 0, stream,
                       in, w_in, b_in, w_rec, b_rec, w_key, b_key, z, out);
}

// Round 2
// 109270.496 us; speedup vs baseline: 1.1632x; 1.1632x over previous
//
#include <hip/hip_runtime.h>
#include <math.h>

#define BB   256
#define TN   1024
#define HH   512
#define MB   4
#define NTHR 1024
#define NBLK (BB/MB)

#define OFF_KEYS 0L
#define OFF_PRS  524288L
#define OFF_HS   1572864L
#define OFF_TM   135790592L

typedef float f32x4 __attribute__((ext_vector_type(4)));

__device__ __forceinline__ float sigm(float x) { return 1.0f / (1.0f + expf(-x)); }

#define FMA4(ACC, W, H0, H1, H2, H3)                                  \
    ACC[0] = fmaf(W.x, H0.x, fmaf(W.y, H0.y, fmaf(W.z, H0.z, fmaf(W.w, H0.w, ACC[0])))); \
    ACC[1] = fmaf(W.x, H1.x, fmaf(W.y, H1.y, fmaf(W.z, H1.z, fmaf(W.w, H1.w, ACC[1])))); \
    ACC[2] = fmaf(W.x, H2.x, fmaf(W.y, H2.y, fmaf(W.z, H2.z, fmaf(W.w, H2.w, ACC[2])))); \
    ACC[3] = fmaf(W.x, H3.x, fmaf(W.y, H3.y, fmaf(W.z, H3.z, fmaf(W.w, H3.w, ACC[3]))));

__global__ __launch_bounds__(NTHR, 4) void rnn_fused(
    const float* __restrict__ in,
    const float* __restrict__ w_in, const float* __restrict__ b_in,
    const float* __restrict__ w_rec, const float* __restrict__ b_rec,
    const float* __restrict__ w_key, const float* __restrict__ b_key,
    const float* __restrict__ z,
    float* __restrict__ out)
{
    __shared__ __align__(16) float tbuf[MB][HH][8];    // 64 KB: 8-step hs tile
    __shared__ __align__(16) float hbuf[MB][HH];       // 8 KB: h state
    __shared__ float wi_sh[HH][6];                     // 12 KB
    __shared__ float bsum[HH];                         // 2 KB
    __shared__ float wk[2][HH];                        // 4 KB
    __shared__ float keysT[2][MB][2][16];              // 1 KB
    __shared__ float prsT[2][MB][4][16];               // 2 KB
    __shared__ float tmT[2][MB][16];                   // 0.5 KB
    __shared__ float inp6[MB][8];
    __shared__ float kred[16][MB][2];
    __shared__ int   idx_sh[MB];

    const int tid = threadIdx.x;
    const int b0  = blockIdx.x * MB;
    const int gr  = tid >> 4;     // 64 groups of 16 lanes
    const int g   = tid & 15;
    const int wv  = tid >> 6;     // wave id
    const int ln  = tid & 63;

    // ---------------- init ----------------
    for (int i = tid; i < MB * HH; i += NTHR) {
        int b = i >> 9, j = i & (HH - 1);
        hbuf[b][j]    = 0.0f;   // h at t=0
        tbuf[b][j][0] = 0.0f;   // hs column t=0
    }
    if (tid < HH) {
        bsum[tid]  = b_in[tid] + b_rec[tid];
        wk[0][tid] = w_key[tid];
        wk[1][tid] = w_key[HH + tid];
        #pragma unroll
        for (int c = 0; c < 6; ++c) wi_sh[tid][c] = w_in[tid * 6 + c];
    }
    if (tid < MB) {
        keysT[0][tid][0][0] = 0.0f; keysT[0][tid][1][0] = 0.0f;
        prsT[0][tid][0][0] = 0.0f; prsT[0][tid][1][0] = 0.0f;
        prsT[0][tid][2][0] = 0.0f; prsT[0][tid][3][0] = 0.0f;
        tmT[0][tid][0] = in[(long)(b0 + tid) * 8 * TN + 7 * TN];  // tm2[:,0]
    }
    // argmax(tm1[b,:]) first-occurrence, one wave per batch
    if (wv < MB) {
        const float* tm1p = in + (long)(b0 + wv) * 8 * TN + 6 * TN;
        float bv = -3.0e38f; int bi = 0;
        for (int i = 0; i < TN / 64; ++i) {
            int t = i * 64 + ln;
            float v = tm1p[t];
            if (v > bv) { bv = v; bi = t; }
        }
        for (int m = 1; m < 64; m <<= 1) {
            float ov = __shfl_xor(bv, m);
            int   oi = __shfl_xor(bi, m);
            if (ov > bv || (ov == bv && oi < bi)) { bv = ov; bi = oi; }
        }
        if (ln == 0) idx_sh[wv] = bi;
    }
    // tm_modified[:,0,:] = tm1 (full row, nt float4)
    {
        int b = tid >> 8, tq = tid & 255;
        f32x4 v = *(const f32x4*)(in + (long)(b0 + b) * 8 * TN + 6 * TN + tq * 4);
        __builtin_nontemporal_store(v, (f32x4*)(out + OFF_TM + (long)(b0 + b) * 2 * TN + tq * 4));
    }

    // t-invariant weight row pointers (8 rows per 16-lane group)
    const float* wrow[8];
    #pragma unroll
    for (int r = 0; r < 8; ++r) wrow[r] = w_rec + (long)(r * 64 + gr) * HH + g * 4;

    float kh = 1.0f, off = 0.0f;     // carries for lanes tid<4 (batch b=tid)
    int side_pre = 1;
    const float bk0 = b_key[0], bk1 = b_key[1];
    __syncthreads();
    const int idxm = (tid < MB) ? idx_sh[tid] : 0;

    // ---------------- time loop ----------------
    for (int t = 1; t < TN; ++t) {
        // prefetch kk=0, rows 0-3 (no dependence on stage)
        f32x4 wA[4], wB[4];
        #pragma unroll
        for (int r = 0; r < 4; ++r) wA[r] = *(const f32x4*)(wrow[r]);

        // ---- stage (lanes 0-3), overlapped with other waves' GEMV ----
        if (tid < MB) {
            const float* inb = in + (long)(b0 + tid) * 8 * TN;
            const float ap0 = inb[t],          ap1 = inb[TN + t];
            const float a0  = inb[2 * TN + t], a1  = inb[3 * TN + t];
            const float a2  = inb[4 * TN + t], a3  = inb[5 * TN + t];
            const float t1  = inb[6 * TN + t], t2o = inb[7 * TN + t];
            const float zt  = z[(long)(t - 1) * BB + b0 + tid];
            const int side  = (kh > 0.5f);
            const float asum0 = a0 * kh + a2 * (1.0f - kh);
            const float asum1 = a1 * kh + a3 * (1.0f - kh);
            const int closer1 = (fabsf(ap0 - t1) <= fabsf(ap1 - t1));
            const int done    = (t > idxm);
            const int switched = ((side != side_pre) && done && (side != closer1));
            const float t2c = t2o + off;
            if (switched) off += zt * fabsf(0.05f * t2c);
            const float t2e = t2o + off;
            side_pre = side;
            float q0 = (t1 - ap0) / (0.15f * ap0);      float pr10 = (t1 == 0.0f) ? 0.0f : q0 * q0;
            float q1 = (t1 - ap1) / (0.15f * ap1);      float pr11 = (t1 == 0.0f) ? 0.0f : q1 * q1;
            float q2 = (t2e - asum0) / (0.15f * asum0); float pr20 = (t2e == 0.0f) ? 0.0f : q2 * q2;
            float q3 = (t2e - asum1) / (0.15f * asum1); float pr21 = (t2e == 0.0f) ? 0.0f : q3 * q3;
            const int tb = (t >> 4) & 1, sl = t & 15;
            prsT[tb][tid][0][sl] = pr10; prsT[tb][tid][1][sl] = pr11;
            prsT[tb][tid][2][sl] = pr20; prsT[tb][tid][3][sl] = pr21;
            tmT[tb][tid][sl] = t2e;
            inp6[tid][0] = ap0; inp6[tid][1] = ap1; inp6[tid][2] = asum0;
            inp6[tid][3] = asum1; inp6[tid][4] = t1; inp6[tid][5] = t2e;
        }

        // ---- GEMV: double-buffered weight regs, 8 rows x 4 batches ----
        float acc[8][4];
        #pragma unroll
        for (int r = 0; r < 8; ++r) { acc[r][0] = 0.f; acc[r][1] = 0.f; acc[r][2] = 0.f; acc[r][3] = 0.f; }
        const float* hb = &hbuf[0][0];
        #pragma unroll
        for (int kk = 0; kk < 8; ++kk) {
            const int k0 = kk * 64 + (g << 2);
            const f32x4 h0 = *(const f32x4*)(hb + 0 * HH + k0);
            const f32x4 h1 = *(const f32x4*)(hb + 1 * HH + k0);
            const f32x4 h2 = *(const f32x4*)(hb + 2 * HH + k0);
            const f32x4 h3 = *(const f32x4*)(hb + 3 * HH + k0);
            #pragma unroll
            for (int r = 0; r < 4; ++r) wB[r] = *(const f32x4*)(wrow[r + 4] + kk * 64);
            #pragma unroll
            for (int r = 0; r < 4; ++r) { FMA4(acc[r], wA[r], h0, h1, h2, h3); }
            if (kk < 7) {
                #pragma unroll
                for (int r = 0; r < 4; ++r) wA[r] = *(const f32x4*)(wrow[r] + (kk + 1) * 64);
            }
            #pragma unroll
            for (int r = 0; r < 4; ++r) { FMA4(acc[r + 4], wB[r], h0, h1, h2, h3); }
        }
        // 16-lane butterfly reduce
        #pragma unroll
        for (int r = 0; r < 8; ++r) {
            #pragma unroll
            for (int b = 0; b < MB; ++b) {
                float v = acc[r][b];
                v += __shfl_xor(v, 1, 16);
                v += __shfl_xor(v, 2, 16);
                v += __shfl_xor(v, 4, 16);
                v += __shfl_xor(v, 8, 16);
                acc[r][b] = v;
            }
        }
        __syncthreads();   // A: GEMV h-reads done; inp6/prsT/tmT visible

        // ---- finalize: lanes g<4 own batch b=g for this group's 8 rows ----
        float kacc0 = 0.0f, kacc1 = 0.0f;
        if (g < MB) {
            const int b = g;
            const float i0 = inp6[b][0], i1 = inp6[b][1], i2 = inp6[b][2];
            const float i3 = inp6[b][3], i4 = inp6[b][4], i5 = inp6[b][5];
            #pragma unroll
            for (int r = 0; r < 8; ++r) {
                const int j = r * 64 + gr;
                float s = acc[r][b] + bsum[j]
                        + wi_sh[j][0] * i0 + wi_sh[j][1] * i1 + wi_sh[j][2] * i2
                        + wi_sh[j][3] * i3 + wi_sh[j][4] * i4 + wi_sh[j][5] * i5;
                const float h = tanhf(s);
                hbuf[b][j]         = h;
                tbuf[b][j][t & 7]  = h;
                kacc0 = fmaf(h, wk[0][j], kacc0);
                kacc1 = fmaf(h, wk[1][j], kacc1);
            }
        }
        kacc0 += __shfl_xor(kacc0, 16); kacc0 += __shfl_xor(kacc0, 32);
        kacc1 += __shfl_xor(kacc1, 16); kacc1 += __shfl_xor(kacc1, 32);
        if (ln < MB) { kred[wv][ln][0] = kacc0; kred[wv][ln][1] = kacc1; }
        __syncthreads();   // B: hbuf/kred/tbuf visible

        // ---- keys finalize (lanes 0-3) ----
        if (tid < MB) {
            float k0s = 0.0f, k1s = 0.0f;
            #pragma unroll
            for (int w = 0; w < 16; ++w) { k0s += kred[w][tid][0]; k1s += kred[w][tid][1]; }
            const float key0 = sigm(k0s + bk0);
            const float key1 = sigm(k1s + bk1);
            const int tb = (t >> 4) & 1, sl = t & 15;
            keysT[tb][tid][0][sl] = key0;
            keysT[tb][tid][1][sl] = key1;
            kh = key0;
        }

        // ---- hs flush every 8 steps (nt, aligned float4) ----
        if ((t & 7) == 7) {
            const int t0 = t & ~7;
            #pragma unroll
            for (int i = 0; i < 4; ++i) {
                const int f = i * NTHR + tid;          // 0..4095 float4s
                const int b = f >> 10, rem = f & 1023;
                const int j = rem >> 1, q = rem & 1;
                f32x4 v = *(const f32x4*)&tbuf[b][j][q * 4];
                __builtin_nontemporal_store(v,
                    (f32x4*)(out + OFF_HS + ((long)(b0 + b) * HH + j) * TN + t0 + q * 4));
            }
        }
        // ---- keys/prs/tm flush every 16 steps ----
        if ((t & 15) == 15) {
            __syncthreads();   // keysT slot t just written by lanes 0-3
            const int t0 = t & ~15;
            const int tb = (t >> 4) & 1;
            if (tid < 32) {
                const int b = tid >> 3, c = (tid >> 2) & 1, q = tid & 3;
                __builtin_nontemporal_store(*(const f32x4*)&keysT[tb][b][c][q * 4],
                    (f32x4*)(out + OFF_KEYS + (long)(b0 + b) * 2 * TN + c * TN + t0 + q * 4));
            } else if (tid < 96) {
                const int f = tid - 32, b = f >> 4, c = (f >> 2) & 3, q = f & 3;
                __builtin_nontemporal_store(*(const f32x4*)&prsT[tb][b][c][q * 4],
                    (f32x4*)(out + OFF_PRS + (long)(b0 + b) * 4 * TN + c * TN + t0 + q * 4));
            } else if (tid < 112) {
                const int f = tid - 96, b = f >> 2, q = f & 3;
                __builtin_nontemporal_store(*(const f32x4*)&tmT[tb][b][q * 4],
                    (f32x4*)(out + OFF_TM + (long)(b0 + b) * 2 * TN + TN + t0 + q * 4));
            }
        }
    }
}

extern "C" void kernel_launch(void* const* d_in, const int* in_sizes, int n_in,
                              void* d_out, int out_size, void* d_ws, size_t ws_size,
                              hipStream_t stream) {
    (void)in_sizes; (void)n_in; (void)out_size; (void)d_ws; (void)ws_size;
    const float* in    = (const float*)d_in[0];
    const float* w_in  = (const float*)d_in[1];
    const float* b_in  = (const float*)d_in[2];
    const float* w_rec = (const float*)d_in[3];
    const float* b_rec = (const float*)d_in[4];
    const float* w_key = (const float*)d_in[5];
    const float* b_key = (const float*)d_in[6];
    const float* z     = (const float*)d_in[7];
    float* out = (float*)d_out;
    hipLaunchKernelGGL(rnn_fused, dim3(NBLK), dim3(NTHR), 0, stream,
                       in, w_in, b_in, w_rec, b_rec, w_key, b_key, z, out);
}

// Round 3
// 10387.834 us; speedup vs baseline: 12.2356x; 10.5191x over previous
//
#include <hip/hip_runtime.h>
#include <math.h>

#define TN 1024
#define HH 512
#define BB 256
#define NTHR 320

#define OFF_KEYS 0L
#define OFF_PRS  524288L
#define OFF_HS   1572864L
#define OFF_TM   135790592L

typedef float f32x4 __attribute__((ext_vector_type(4)));

__device__ __forceinline__ float sigm(float x) { return 1.0f / (1.0f + expf(-x)); }

__global__ __launch_bounds__(NTHR) void rnn_fused(
    const float* __restrict__ in,
    const float* __restrict__ w_in, const float* __restrict__ b_in,
    const float* __restrict__ w_rec, const float* __restrict__ b_rec,
    const float* __restrict__ w_key, const float* __restrict__ b_key,
    const float* __restrict__ z,
    float* __restrict__ out)
{
    __shared__ __align__(16) float hsh[HH];          // h_{t-1}
    __shared__ __align__(16) float tbuf[2][HH][17];  // hs 16-step tiles, padded (68 KB)
    __shared__ __align__(16) float keysT[2][2][16];
    __shared__ __align__(16) float prsT[2][4][16];
    __shared__ __align__(16) float tmT[2][16];
    __shared__ float wi_sh[HH][6];
    __shared__ float bsum[HH];
    __shared__ float wk2[2][HH];
    __shared__ float inp6[8];
    __shared__ float kred[4][2];

    const int tid = threadIdx.x;
    const int bb  = blockIdx.x;           // one batch per block
    const int wv  = tid >> 6;             // 0..4
    const int ln  = tid & 63;
    const int qd  = tid >> 2;             // quad id (rows qd*8..qd*8+7 for wv<4)
    const int q   = tid & 3;
    const float* inb = in + (long)bb * 8 * TN;

    // ---------------- init ----------------
    if (tid < 256) {
        hsh[tid] = 0.0f; hsh[tid + 256] = 0.0f;
        tbuf[0][tid][0] = 0.0f; tbuf[0][tid + 256][0] = 0.0f;
        bsum[tid]       = b_in[tid]       + b_rec[tid];
        bsum[tid + 256] = b_in[tid + 256] + b_rec[tid + 256];
        wk2[0][tid] = w_key[tid];           wk2[0][tid + 256] = w_key[tid + 256];
        wk2[1][tid] = w_key[HH + tid];      wk2[1][tid + 256] = w_key[HH + tid + 256];
        #pragma unroll
        for (int c = 0; c < 6; ++c) {
            wi_sh[tid][c]       = w_in[tid * 6 + c];
            wi_sh[tid + 256][c] = w_in[(tid + 256) * 6 + c];
        }
        // tm_modified[bb, 0, :] = tm1
        f32x4 v = *(const f32x4*)(inb + 6 * TN + tid * 4);
        __builtin_nontemporal_store(v, (f32x4*)(out + OFF_TM + (long)bb * 2 * TN + tid * 4));
    }
    if (tid == 256) {
        keysT[0][0][0] = 0.0f; keysT[0][1][0] = 0.0f;
        prsT[0][0][0] = 0.0f; prsT[0][1][0] = 0.0f;
        prsT[0][2][0] = 0.0f; prsT[0][3][0] = 0.0f;
        tmT[0][0] = inb[7 * TN];            // tm2[:,0]
    }
    // argmax(tm1) first-occurrence — wave 4
    int idxm = 0;
    if (wv == 4) {
        const float* tm1p = inb + 6 * TN;
        float bv = -3.0e38f; int bi = 0;
        for (int i = 0; i < 16; ++i) {
            int tt = i * 64 + ln;
            float v = tm1p[tt];
            if (v > bv) { bv = v; bi = tt; }
        }
        for (int m = 1; m < 64; m <<= 1) {
            float ov = __shfl_xor(bv, m);
            int   oi = __shfl_xor(bi, m);
            if (ov > bv || (ov == bv && oi < bi)) { bv = ov; bi = oi; }
        }
        idxm = bi;
    }
    float kh = 1.0f, off = 0.0f;
    int side_pre = 1;
    __syncthreads();

    // ---------------- time loop ----------------
    for (int t = 1; t < TN; ++t) {
        const int tile = (t >> 4) & 1, sl = t & 15;
        float s0 = 0.0f, s1 = 0.0f;

        if (wv < 4) {
            // ---- GEMV rows qd*8..+7, K-split 4 lanes x 4 floats ----
            float acc[8] = {0,0,0,0,0,0,0,0};
            const float* wbase = w_rec + (long)(qd * 8) * HH + q * 4;
            #pragma unroll 4
            for (int kk = 0; kk < 32; ++kk) {
                const f32x4 h4 = *(const f32x4*)&hsh[kk * 16 + q * 4];
                #pragma unroll
                for (int r = 0; r < 8; ++r) {
                    const f32x4 w4 = *(const f32x4*)(wbase + r * HH + kk * 16);
                    acc[r] = fmaf(w4.x, h4.x, fmaf(w4.y, h4.y,
                             fmaf(w4.z, h4.z, fmaf(w4.w, h4.w, acc[r]))));
                }
            }
            // distributing reduce: lane q ends with rows qd*8+q (s0), qd*8+q+4 (s1)
            const bool qb0 = (q & 1), qb1 = (q & 2);
            float p0 = (qb0 ? acc[1] : acc[0]) + __shfl_xor(qb0 ? acc[0] : acc[1], 1, 4);
            float p1 = (qb0 ? acc[3] : acc[2]) + __shfl_xor(qb0 ? acc[2] : acc[3], 1, 4);
            float p2 = (qb0 ? acc[5] : acc[4]) + __shfl_xor(qb0 ? acc[4] : acc[5], 1, 4);
            float p3 = (qb0 ? acc[7] : acc[6]) + __shfl_xor(qb0 ? acc[6] : acc[7], 1, 4);
            s0 = (qb1 ? p1 : p0) + __shfl_xor(qb1 ? p0 : p1, 2, 4);
            s1 = (qb1 ? p3 : p2) + __shfl_xor(qb1 ? p2 : p3, 2, 4);
        } else if (tid == 256) {
            // ---- keys of t-1, then stage(t) ----
            if (t > 1) {
                float k0 = kred[0][0] + kred[1][0] + kred[2][0] + kred[3][0];
                float k1 = kred[0][1] + kred[1][1] + kred[2][1] + kred[3][1];
                const float key0 = sigm(k0 + b_key[0]);
                const float key1 = sigm(k1 + b_key[1]);
                const int pt = t - 1;
                keysT[(pt >> 4) & 1][0][pt & 15] = key0;
                keysT[(pt >> 4) & 1][1][pt & 15] = key1;
                kh = key0;
            }
            const float ap0 = inb[t],          ap1 = inb[TN + t];
            const float a0  = inb[2 * TN + t], a1  = inb[3 * TN + t];
            const float a2  = inb[4 * TN + t], a3  = inb[5 * TN + t];
            const float t1  = inb[6 * TN + t], t2o = inb[7 * TN + t];
            const float zt  = z[(long)(t - 1) * BB + bb];
            const int side  = (kh > 0.5f);
            const float asum0 = a0 * kh + a2 * (1.0f - kh);
            const float asum1 = a1 * kh + a3 * (1.0f - kh);
            const int closer1  = (fabsf(ap0 - t1) <= fabsf(ap1 - t1));
            const int done     = (t > idxm);
            const int switched = ((side != side_pre) && done && (side != closer1));
            const float t2c = t2o + off;
            if (switched) off += zt * fabsf(0.05f * t2c);
            const float t2e = t2o + off;
            side_pre = side;
            float u0 = (t1 - ap0) / (0.15f * ap0);      float pr10 = (t1 == 0.0f)  ? 0.0f : u0 * u0;
            float u1 = (t1 - ap1) / (0.15f * ap1);      float pr11 = (t1 == 0.0f)  ? 0.0f : u1 * u1;
            float u2 = (t2e - asum0) / (0.15f * asum0); float pr20 = (t2e == 0.0f) ? 0.0f : u2 * u2;
            float u3 = (t2e - asum1) / (0.15f * asum1); float pr21 = (t2e == 0.0f) ? 0.0f : u3 * u3;
            prsT[tile][0][sl] = pr10; prsT[tile][1][sl] = pr11;
            prsT[tile][2][sl] = pr20; prsT[tile][3][sl] = pr21;
            tmT[tile][sl] = t2e;
            inp6[0] = ap0; inp6[1] = ap1; inp6[2] = asum0;
            inp6[3] = asum1; inp6[4] = t1; inp6[5] = t2e;
        }
        __syncthreads();   // B: GEMV h-reads done; inp6/kred-consumption ordered

        if (wv < 4) {
            // ---- finalize rows j0=qd*8+q, j1=j0+4 ----
            const int j0 = qd * 8 + q, j1 = j0 + 4;
            const float i0 = inp6[0], i1 = inp6[1], i2 = inp6[2];
            const float i3 = inp6[3], i4 = inp6[4], i5 = inp6[5];
            float sm0 = s0 + bsum[j0]
                      + wi_sh[j0][0] * i0 + wi_sh[j0][1] * i1 + wi_sh[j0][2] * i2
                      + wi_sh[j0][3] * i3 + wi_sh[j0][4] * i4 + wi_sh[j0][5] * i5;
            float sm1 = s1 + bsum[j1]
                      + wi_sh[j1][0] * i0 + wi_sh[j1][1] * i1 + wi_sh[j1][2] * i2
                      + wi_sh[j1][3] * i3 + wi_sh[j1][4] * i4 + wi_sh[j1][5] * i5;
            const float h0v = tanhf(sm0);
            const float h1v = tanhf(sm1);
            hsh[j0] = h0v; hsh[j1] = h1v;
            tbuf[tile][j0][sl] = h0v; tbuf[tile][j1][sl] = h1v;
            float ka0 = h0v * wk2[0][j0] + h1v * wk2[0][j1];
            float ka1 = h0v * wk2[1][j0] + h1v * wk2[1][j1];
            #pragma unroll
            for (int m = 1; m < 64; m <<= 1) { ka0 += __shfl_xor(ka0, m); ka1 += __shfl_xor(ka1, m); }
            if (ln == 0) { kred[wv][0] = ka0; kred[wv][1] = ka1; }
        } else if ((t & 15) == 0) {
            // ---- wave 4: flush previous 16-step tile (f = tile^1, t0 = t-16) ----
            const int f = tile ^ 1;
            const int t0 = t - 16;
            if (ln < 8) {
                const int ch = ln >> 2, q4 = ln & 3;
                __builtin_nontemporal_store(*(const f32x4*)&keysT[f][ch][q4 * 4],
                    (f32x4*)(out + OFF_KEYS + (long)bb * 2 * TN + ch * TN + t0 + q4 * 4));
            } else if (ln < 24) {
                const int ix = ln - 8, ch = ix >> 2, q4 = ix & 3;
                __builtin_nontemporal_store(*(const f32x4*)&prsT[f][ch][q4 * 4],
                    (f32x4*)(out + OFF_PRS + (long)bb * 4 * TN + ch * TN + t0 + q4 * 4));
            } else if (ln < 28) {
                const int q4 = ln - 24;
                __builtin_nontemporal_store(*(const f32x4*)&tmT[f][q4 * 4],
                    (f32x4*)(out + OFF_TM + (long)bb * 2 * TN + TN + t0 + q4 * 4));
            }
            #pragma unroll
            for (int k2 = 0; k2 < 8; ++k2) {
                const int j = ln + 64 * k2;
                const float* tr = &tbuf[f][j][0];
                #pragma unroll
                for (int c = 0; c < 4; ++c) {
                    f32x4 v;
                    v.x = tr[c * 4]; v.y = tr[c * 4 + 1]; v.z = tr[c * 4 + 2]; v.w = tr[c * 4 + 3];
                    __builtin_nontemporal_store(v,
                        (f32x4*)(out + OFF_HS + ((long)bb * HH + j) * TN + t0 + c * 4));
                }
            }
        }
        __syncthreads();   // D: hsh/kred/tbuf visible for next iteration
    }

    // ---------------- epilogue: key_1023 + final tile flush ----------------
    if (tid == 256) {
        float k0 = kred[0][0] + kred[1][0] + kred[2][0] + kred[3][0];
        float k1 = kred[0][1] + kred[1][1] + kred[2][1] + kred[3][1];
        keysT[1][0][15] = sigm(k0 + b_key[0]);
        keysT[1][1][15] = sigm(k1 + b_key[1]);
    }
    __syncthreads();
    if (wv == 4) {
        const int f = 1, t0 = TN - 16;
        if (ln < 8) {
            const int ch = ln >> 2, q4 = ln & 3;
            __builtin_nontemporal_store(*(const f32x4*)&keysT[f][ch][q4 * 4],
                (f32x4*)(out + OFF_KEYS + (long)bb * 2 * TN + ch * TN + t0 + q4 * 4));
        } else if (ln < 24) {
            const int ix = ln - 8, ch = ix >> 2, q4 = ix & 3;
            __builtin_nontemporal_store(*(const f32x4*)&prsT[f][ch][q4 * 4],
                (f32x4*)(out + OFF_PRS + (long)bb * 4 * TN + ch * TN + t0 + q4 * 4));
        } else if (ln < 28) {
            const int q4 = ln - 24;
            __builtin_nontemporal_store(*(const f32x4*)&tmT[f][q4 * 4],
                (f32x4*)(out + OFF_TM + (long)bb * 2 * TN + TN + t0 + q4 * 4));
        }
        #pragma unroll
        for (int k2 = 0; k2 < 8; ++k2) {
            const int j = ln + 64 * k2;
            const float* tr = &tbuf[f][j][0];
            #pragma unroll
            for (int c = 0; c < 4; ++c) {
                f32x4 v;
                v.x = tr[c * 4]; v.y = tr[c * 4 + 1]; v.z = tr[c * 4 + 2]; v.w = tr[c * 4 + 3];
                __builtin_nontemporal_store(v,
                    (f32x4*)(out + OFF_HS + ((long)bb * HH + j) * TN + t0 + c * 4));
            }
        }
    }
}

extern "C" void kernel_launch(void* const* d_in, const int* in_sizes, int n_in,
                              void* d_out, int out_size, void* d_ws, size_t ws_size,
                              hipStream_t stream) {
    (void)in_sizes; (void)n_in; (void)out_size; (void)d_ws; (void)ws_size;
    const float* in    = (const float*)d_in[0];
    const float* w_in  = (const float*)d_in[1];
    const float* b_in  = (const float*)d_in[2];
    const float* w_rec = (const float*)d_in[3];
    const float* b_rec = (const float*)d_in[4];
    const float* w_key = (const float*)d_in[5];
    const float* b_key = (const float*)d_in[6];
    const float* z     = (const float*)d_in[7];
    float* out = (float*)d_out;
    hipLaunchKernelGGL(rnn_fused, dim3(BB), dim3(NTHR), 0, stream,
                       in, w_in, b_in, w_rec, b_rec, w_key, b_key, z, out);
}

// Round 4
// 6007.158 us; speedup vs baseline: 21.1583x; 1.7292x over previous
//
#include <hip/hip_runtime.h>
#include <math.h>

#define TN 1024
#define HH 512
#define BB 256
#define NTHR 320

#define OFF_KEYS 0L
#define OFF_PRS  524288L
#define OFF_HS   1572864L
#define OFF_TM   135790592L

typedef float f32x4 __attribute__((ext_vector_type(4)));

__device__ __forceinline__ float sigm(float x) { return 1.0f / (1.0f + expf(-x)); }
__device__ __forceinline__ float bflo(unsigned u) { return __uint_as_float(u << 16); }
__device__ __forceinline__ float bfhi(unsigned u) { return __uint_as_float(u & 0xffff0000u); }

// ---- pre-kernel: RNE-convert w_rec (512x512 f32) to bf16 in d_ws ----
__global__ __launch_bounds__(256) void conv_bf16(const float* __restrict__ w,
                                                 unsigned short* __restrict__ o) {
    const int i = (blockIdx.x * 256 + threadIdx.x) * 4;
    const f32x4 v = *(const f32x4*)(w + i);
    unsigned short r[4];
    #pragma unroll
    for (int k = 0; k < 4; ++k) {
        unsigned u = __float_as_uint(v[k]);
        u += 0x7fffu + ((u >> 16) & 1u);
        r[k] = (unsigned short)(u >> 16);
    }
    *(unsigned long long*)(o + i) = *(unsigned long long*)r;
}

__global__ __launch_bounds__(NTHR) void rnn_fused(
    const float* __restrict__ in,
    const float* __restrict__ w_in, const float* __restrict__ b_in,
    const unsigned short* __restrict__ wbf, const float* __restrict__ b_rec,
    const float* __restrict__ w_key, const float* __restrict__ b_key,
    const float* __restrict__ z,
    float* __restrict__ out)
{
    __shared__ __align__(16) float hsh[HH];          // h_{t-1}
    __shared__ __align__(16) float tbuf[2][HH][17];  // hs 16-step tiles, padded (68 KB)
    __shared__ __align__(16) float keysT[2][2][16];
    __shared__ __align__(16) float prsT[2][4][16];
    __shared__ __align__(16) float tmT[2][16];
    __shared__ float wi_sh[HH][6];
    __shared__ float bsum[HH];
    __shared__ float wk2[2][HH];
    __shared__ float inp6[8];
    __shared__ float kred[4][2];

    const int tid = threadIdx.x;
    const int bb  = blockIdx.x;           // one batch per block
    const int wv  = tid >> 6;             // 0..4
    const int ln  = tid & 63;
    const int qd  = tid >> 2;             // quad id (rows qd*8..qd*8+7 for wv<4)
    const int q   = tid & 3;
    const float* inb = in + (long)bb * 8 * TN;

    // ---------------- init ----------------
    if (tid < 256) {
        hsh[tid] = 0.0f; hsh[tid + 256] = 0.0f;
        tbuf[0][tid][0] = 0.0f; tbuf[0][tid + 256][0] = 0.0f;
        bsum[tid]       = b_in[tid]       + b_rec[tid];
        bsum[tid + 256] = b_in[tid + 256] + b_rec[tid + 256];
        wk2[0][tid] = w_key[tid];           wk2[0][tid + 256] = w_key[tid + 256];
        wk2[1][tid] = w_key[HH + tid];      wk2[1][tid + 256] = w_key[HH + tid + 256];
        #pragma unroll
        for (int c = 0; c < 6; ++c) {
            wi_sh[tid][c]       = w_in[tid * 6 + c];
            wi_sh[tid + 256][c] = w_in[(tid + 256) * 6 + c];
        }
        // tm_modified[bb, 0, :] = tm1
        f32x4 v = *(const f32x4*)(inb + 6 * TN + tid * 4);
        __builtin_nontemporal_store(v, (f32x4*)(out + OFF_TM + (long)bb * 2 * TN + tid * 4));
    }
    if (tid == 256) {
        keysT[0][0][0] = 0.0f; keysT[0][1][0] = 0.0f;
        prsT[0][0][0] = 0.0f; prsT[0][1][0] = 0.0f;
        prsT[0][2][0] = 0.0f; prsT[0][3][0] = 0.0f;
        tmT[0][0] = inb[7 * TN];            // tm2[:,0]
    }
    // argmax(tm1) first-occurrence — wave 4
    int idxm = 0;
    if (wv == 4) {
        const float* tm1p = inb + 6 * TN;
        float bv = -3.0e38f; int bi = 0;
        for (int i = 0; i < 16; ++i) {
            int tt = i * 64 + ln;
            float v = tm1p[tt];
            if (v > bv) { bv = v; bi = tt; }
        }
        for (int m = 1; m < 64; m <<= 1) {
            float ov = __shfl_xor(bv, m);
            int   oi = __shfl_xor(bi, m);
            if (ov > bv || (ov == bv && oi < bi)) { bv = ov; bi = oi; }
        }
        idxm = bi;
    }
    float kh = 1.0f, off = 0.0f;
    int side_pre = 1;
    __syncthreads();

    // ---------------- time loop ----------------
    for (int t = 1; t < TN; ++t) {
        const int tile = (t >> 4) & 1, sl = t & 15;
        float s0 = 0.0f, s1 = 0.0f;

        if (wv < 4) {
            // ---- GEMV rows qd*8..+7, bf16 weights, K-split 4 lanes x 8 ----
            float acc[8] = {0,0,0,0,0,0,0,0};
            const unsigned short* wbase = wbf + (long)(qd * 8) * HH + q * 8;
            #pragma unroll 2
            for (int kk = 0; kk < 16; ++kk) {
                const int k0 = kk * 32 + q * 8;
                const f32x4 ha = *(const f32x4*)&hsh[k0];
                const f32x4 hb = *(const f32x4*)&hsh[k0 + 4];
                #pragma unroll
                for (int r = 0; r < 8; ++r) {
                    const uint4 wu = *(const uint4*)(wbase + r * HH + kk * 32);
                    acc[r] = fmaf(bflo(wu.x), ha.x, fmaf(bfhi(wu.x), ha.y,
                             fmaf(bflo(wu.y), ha.z, fmaf(bfhi(wu.y), ha.w,
                             fmaf(bflo(wu.z), hb.x, fmaf(bfhi(wu.z), hb.y,
                             fmaf(bflo(wu.w), hb.z, fmaf(bfhi(wu.w), hb.w, acc[r]))))))));
                }
            }
            // distributing reduce: lane q ends with rows qd*8+q (s0), qd*8+q+4 (s1)
            const bool qb0 = (q & 1), qb1 = (q & 2);
            float p0 = (qb0 ? acc[1] : acc[0]) + __shfl_xor(qb0 ? acc[0] : acc[1], 1, 4);
            float p1 = (qb0 ? acc[3] : acc[2]) + __shfl_xor(qb0 ? acc[2] : acc[3], 1, 4);
            float p2 = (qb0 ? acc[5] : acc[4]) + __shfl_xor(qb0 ? acc[4] : acc[5], 1, 4);
            float p3 = (qb0 ? acc[7] : acc[6]) + __shfl_xor(qb0 ? acc[6] : acc[7], 1, 4);
            s0 = (qb1 ? p1 : p0) + __shfl_xor(qb1 ? p0 : p1, 2, 4);
            s1 = (qb1 ? p3 : p2) + __shfl_xor(qb1 ? p2 : p3, 2, 4);
        } else if (tid == 256) {
            // ---- keys of t-1, then stage(t) ----
            if (t > 1) {
                float k0 = kred[0][0] + kred[1][0] + kred[2][0] + kred[3][0];
                float k1 = kred[0][1] + kred[1][1] + kred[2][1] + kred[3][1];
                const float key0 = sigm(k0 + b_key[0]);
                const float key1 = sigm(k1 + b_key[1]);
                const int pt = t - 1;
                keysT[(pt >> 4) & 1][0][pt & 15] = key0;
                keysT[(pt >> 4) & 1][1][pt & 15] = key1;
                kh = key0;
            }
            const float ap0 = inb[t],          ap1 = inb[TN + t];
            const float a0  = inb[2 * TN + t], a1  = inb[3 * TN + t];
            const float a2  = inb[4 * TN + t], a3  = inb[5 * TN + t];
            const float t1  = inb[6 * TN + t], t2o = inb[7 * TN + t];
            const float zt  = z[(long)(t - 1) * BB + bb];
            const int side  = (kh > 0.5f);
            const float asum0 = a0 * kh + a2 * (1.0f - kh);
            const float asum1 = a1 * kh + a3 * (1.0f - kh);
            const int closer1  = (fabsf(ap0 - t1) <= fabsf(ap1 - t1));
            const int done     = (t > idxm);
            const int switched = ((side != side_pre) && done && (side != closer1));
            const float t2c = t2o + off;
            if (switched) off += zt * fabsf(0.05f * t2c);
            const float t2e = t2o + off;
            side_pre = side;
            float u0 = (t1 - ap0) / (0.15f * ap0);      float pr10 = (t1 == 0.0f)  ? 0.0f : u0 * u0;
            float u1 = (t1 - ap1) / (0.15f * ap1);      float pr11 = (t1 == 0.0f)  ? 0.0f : u1 * u1;
            float u2 = (t2e - asum0) / (0.15f * asum0); float pr20 = (t2e == 0.0f) ? 0.0f : u2 * u2;
            float u3 = (t2e - asum1) / (0.15f * asum1); float pr21 = (t2e == 0.0f) ? 0.0f : u3 * u3;
            prsT[tile][0][sl] = pr10; prsT[tile][1][sl] = pr11;
            prsT[tile][2][sl] = pr20; prsT[tile][3][sl] = pr21;
            tmT[tile][sl] = t2e;
            inp6[0] = ap0; inp6[1] = ap1; inp6[2] = asum0;
            inp6[3] = asum1; inp6[4] = t1; inp6[5] = t2e;
        }
        __syncthreads();   // B: GEMV h-reads done; inp6 ready

        if (wv < 4) {
            // ---- finalize rows j0=qd*8+q, j1=j0+4 ----
            const int j0 = qd * 8 + q, j1 = j0 + 4;
            const float i0 = inp6[0], i1 = inp6[1], i2 = inp6[2];
            const float i3 = inp6[3], i4 = inp6[4], i5 = inp6[5];
            float sm0 = s0 + bsum[j0]
                      + wi_sh[j0][0] * i0 + wi_sh[j0][1] * i1 + wi_sh[j0][2] * i2
                      + wi_sh[j0][3] * i3 + wi_sh[j0][4] * i4 + wi_sh[j0][5] * i5;
            float sm1 = s1 + bsum[j1]
                      + wi_sh[j1][0] * i0 + wi_sh[j1][1] * i1 + wi_sh[j1][2] * i2
                      + wi_sh[j1][3] * i3 + wi_sh[j1][4] * i4 + wi_sh[j1][5] * i5;
            const float h0v = tanhf(sm0);
            const float h1v = tanhf(sm1);
            hsh[j0] = h0v; hsh[j1] = h1v;
            tbuf[tile][j0][sl] = h0v; tbuf[tile][j1][sl] = h1v;
            float ka0 = h0v * wk2[0][j0] + h1v * wk2[0][j1];
            float ka1 = h0v * wk2[1][j0] + h1v * wk2[1][j1];
            #pragma unroll
            for (int m = 1; m < 64; m <<= 1) { ka0 += __shfl_xor(ka0, m); ka1 += __shfl_xor(ka1, m); }
            if (ln == 0) { kred[wv][0] = ka0; kred[wv][1] = ka1; }
        } else if ((t & 15) == 0) {
            // ---- wave 4: flush previous 16-step tile ----
            const int f = tile ^ 1;
            const int t0 = t - 16;
            if (ln < 8) {
                const int ch = ln >> 2, q4 = ln & 3;
                __builtin_nontemporal_store(*(const f32x4*)&keysT[f][ch][q4 * 4],
                    (f32x4*)(out + OFF_KEYS + (long)bb * 2 * TN + ch * TN + t0 + q4 * 4));
            } else if (ln < 24) {
                const int ix = ln - 8, ch = ix >> 2, q4 = ix & 3;
                __builtin_nontemporal_store(*(const f32x4*)&prsT[f][ch][q4 * 4],
                    (f32x4*)(out + OFF_PRS + (long)bb * 4 * TN + ch * TN + t0 + q4 * 4));
            } else if (ln < 28) {
                const int q4 = ln - 24;
                __builtin_nontemporal_store(*(const f32x4*)&tmT[f][q4 * 4],
                    (f32x4*)(out + OFF_TM + (long)bb * 2 * TN + TN + t0 + q4 * 4));
            }
            #pragma unroll
            for (int k2 = 0; k2 < 8; ++k2) {
                const int j = ln + 64 * k2;
                const float* tr = &tbuf[f][j][0];
                #pragma unroll
                for (int c = 0; c < 4; ++c) {
                    f32x4 v;
                    v.x = tr[c * 4]; v.y = tr[c * 4 + 1]; v.z = tr[c * 4 + 2]; v.w = tr[c * 4 + 3];
                    __builtin_nontemporal_store(v,
                        (f32x4*)(out + OFF_HS + ((long)bb * HH + j) * TN + t0 + c * 4));
                }
            }
        }
        __syncthreads();   // D: hsh/kred/tbuf visible for next iteration
    }

    // ---------------- epilogue ----------------
    if (tid == 256) {
        float k0 = kred[0][0] + kred[1][0] + kred[2][0] + kred[3][0];
        float k1 = kred[0][1] + kred[1][1] + kred[2][1] + kred[3][1];
        keysT[1][0][15] = sigm(k0 + b_key[0]);
        keysT[1][1][15] = sigm(k1 + b_key[1]);
    }
    __syncthreads();
    if (wv == 4) {
        const int f = 1, t0 = TN - 16;
        if (ln < 8) {
            const int ch = ln >> 2, q4 = ln & 3;
            __builtin_nontemporal_store(*(const f32x4*)&keysT[f][ch][q4 * 4],
                (f32x4*)(out + OFF_KEYS + (long)bb * 2 * TN + ch * TN + t0 + q4 * 4));
        } else if (ln < 24) {
            const int ix = ln - 8, ch = ix >> 2, q4 = ix & 3;
            __builtin_nontemporal_store(*(const f32x4*)&prsT[f][ch][q4 * 4],
                (f32x4*)(out + OFF_PRS + (long)bb * 4 * TN + ch * TN + t0 + q4 * 4));
        } else if (ln < 28) {
            const int q4 = ln - 24;
            __builtin_nontemporal_store(*(const f32x4*)&tmT[f][q4 * 4],
                (f32x4*)(out + OFF_TM + (long)bb * 2 * TN + TN + t0 + q4 * 4));
        }
        #pragma unroll
        for (int k2 = 0; k2 < 8; ++k2) {
            const int j = ln + 64 * k2;
            const float* tr = &tbuf[f][j][0];
            #pragma unroll
            for (int c = 0; c < 4; ++c) {
                f32x4 v;
                v.x = tr[c * 4]; v.y = tr[c * 4 + 1]; v.z = tr[c * 4 + 2]; v.w = tr[c * 4 + 3];
                __builtin_nontemporal_store(v,
                    (f32x4*)(out + OFF_HS + ((long)bb * HH + j) * TN + t0 + c * 4));
            }
        }
    }
}

extern "C" void kernel_launch(void* const* d_in, const int* in_sizes, int n_in,
                              void* d_out, int out_size, void* d_ws, size_t ws_size,
                              hipStream_t stream) {
    (void)in_sizes; (void)n_in; (void)out_size; (void)ws_size;
    const float* in    = (const float*)d_in[0];
    const float* w_in  = (const float*)d_in[1];
    const float* b_in  = (const float*)d_in[2];
    const float* w_rec = (const float*)d_in[3];
    const float* b_rec = (const float*)d_in[4];
    const float* w_key = (const float*)d_in[5];
    const float* b_key = (const float*)d_in[6];
    const float* z     = (const float*)d_in[7];
    float* out = (float*)d_out;
    unsigned short* wbf = (unsigned short*)d_ws;   // 512 KB of scratch

    hipLaunchKernelGGL(conv_bf16, dim3(HH * HH / 1024), dim3(256), 0, stream, w_rec, wbf);
    hipLaunchKernelGGL(rnn_fused, dim3(BB), dim3(NTHR), 0, stream,
                       in, w_in, b_in, wbf, b_rec, w_key, b_key, z, out);
}